// Round 5
// baseline (31839.050 us; speedup 1.0000x reference)
//
#include <hip/hip_runtime.h>
#include <hip/hip_bf16.h>

#define HH 20
#define NG 80          // 4*HH gates (i,f,g,o)
#define TSTEPS 256
#define FF 64
#define BLK 256

__device__ __forceinline__ float fast_sigm(float x) {
    float e = __expf(-x);                          // [0, inf)
    return __builtin_amdgcn_rcpf(1.0f + e);        // rcp(inf) = 0, safe
}
__device__ __forceinline__ float fast_tanh(float x) {
    float ax = fabsf(x);
    float e = __expf(-2.0f * ax);                  // (0, 1], never overflows
    float r = (1.0f - e) * __builtin_amdgcn_rcpf(1.0f + e);
    return copysignf(r, x);
}

// All weights/biases read directly from pristine d_in (fp32). Weight reads are
// wave-uniform -> compiler scalarizes to s_load feeding v_fmac SGPR operand.
__global__ __launch_bounds__(BLK) void lstm_fused(
    const float* __restrict__ diag,
    const float* __restrict__ Wih1,                 // [80] (in_dim = 1)
    const float* __restrict__ Whh1,                 // [80][20] row-major
    const float* __restrict__ bih1, const float* __restrict__ bhh1,
    const float* __restrict__ Wih2,                 // [80][20]
    const float* __restrict__ Whh2,                 // [80][20]
    const float* __restrict__ bih2, const float* __restrict__ bhh2,
    const float* __restrict__ W1,  const float* __restrict__ b1,   // [64][20], [64]
    const float* __restrict__ W2,  const float* __restrict__ b2,   // [64], [1]
    float* __restrict__ out, int Btot)
{
    // h-state in LDS [k][tid]: lane stride 4B = 2-way bank alias (free).
    // Each thread touches only its own column -> no barriers needed.
    __shared__ float sh1[HH][BLK];
    __shared__ float sh2[HH][BLK];
    const int tid = threadIdx.x;
    const int b = blockIdx.x * BLK + tid;
    if (b >= Btot) return;

    float c1[HH], c2[HH];
    #pragma unroll
    for (int u = 0; u < HH; ++u) {
        c1[u] = 0.0f; c2[u] = 0.0f;
        sh1[u][tid] = 0.0f; sh2[u][tid] = 0.0f;
    }

    const float* __restrict__ xr = diag + (long long)b * TSTEPS;
    float x = xr[0];

    #pragma unroll 1
    for (int t = 0; t < TSTEPS; ++t) {
        // prefetch next step's input (wraps on last iter; value unused then)
        float xnext = xr[(t + 1) & (TSTEPS - 1)];

        float z[NG];

        // ---- layer 1: z = x*W_ih1 + (b_ih1 + b_hh1) ----
        #pragma unroll
        for (int g = 0; g < NG; ++g)
            z[g] = fmaf(x, Wih1[g], bih1[g] + bhh1[g]);

        // ---- z += h1 @ W_hh1^T ----  (W row-major [g][k], k rolled)
        #pragma unroll 1
        for (int k = 0; k < HH; ++k) {
            float hk = sh1[k][tid];
            #pragma unroll
            for (int g = 0; g < NG; ++g)
                z[g] = fmaf(hk, Whh1[g * HH + k], z[g]);
        }
        // gates: i=z[0:20] f=z[20:40] g=z[40:60] o=z[60:80]
        #pragma unroll
        for (int u = 0; u < HH; ++u) {
            float cn = fast_sigm(z[HH + u]) * c1[u]
                     + fast_sigm(z[u]) * fast_tanh(z[2 * HH + u]);
            c1[u] = cn;
            sh1[u][tid] = fast_sigm(z[3 * HH + u]) * fast_tanh(cn);
        }

        // ---- layer 2: z = (b_ih2 + b_hh2) + h1_new@W_ih2^T + h2@W_hh2^T ----
        #pragma unroll
        for (int g = 0; g < NG; ++g)
            z[g] = bih2[g] + bhh2[g];

        #pragma unroll 1
        for (int k = 0; k < HH; ++k) {
            float hk = sh1[k][tid];
            #pragma unroll
            for (int g = 0; g < NG; ++g)
                z[g] = fmaf(hk, Wih2[g * HH + k], z[g]);
        }
        #pragma unroll 1
        for (int k = 0; k < HH; ++k) {
            float hk = sh2[k][tid];
            #pragma unroll
            for (int g = 0; g < NG; ++g)
                z[g] = fmaf(hk, Whh2[g * HH + k], z[g]);
        }
        #pragma unroll
        for (int u = 0; u < HH; ++u) {
            float cn = fast_sigm(z[HH + u]) * c2[u]
                     + fast_sigm(z[u]) * fast_tanh(z[2 * HH + u]);
            c2[u] = cn;
            sh2[u][tid] = fast_sigm(z[3 * HH + u]) * fast_tanh(cn);
        }

        x = xnext;
    }

    // ---- head: relu(h2 @ W1^T + b1) -> relu(. @ W2^T + b2) ----
    float hr[HH];
    #pragma unroll
    for (int k = 0; k < HH; ++k) hr[k] = sh2[k][tid];

    float y2 = b2[0];
    #pragma unroll 1
    for (int j = 0; j < FF; ++j) {
        float a = b1[j];
        #pragma unroll
        for (int k = 0; k < HH; ++k)
            a = fmaf(hr[k], W1[j * HH + k], a);
        a = fmaxf(a, 0.0f);
        y2 = fmaf(a, W2[j], y2);
    }
    out[b] = fmaxf(y2, 0.0f);      // fp32 output, per reference dtype
}

extern "C" void kernel_launch(void* const* d_in, const int* in_sizes, int n_in,
                              void* d_out, int out_size, void* d_ws, size_t ws_size,
                              hipStream_t stream)
{
    (void)n_in; (void)ws_size; (void)out_size; (void)d_ws;
    const float* diag = (const float*)d_in[0];
    const float* Wih1 = (const float*)d_in[1];
    const float* Whh1 = (const float*)d_in[2];
    const float* bih1 = (const float*)d_in[3];
    const float* bhh1 = (const float*)d_in[4];
    const float* Wih2 = (const float*)d_in[5];
    const float* Whh2 = (const float*)d_in[6];
    const float* bih2 = (const float*)d_in[7];
    const float* bhh2 = (const float*)d_in[8];
    const float* W1   = (const float*)d_in[9];
    const float* b1   = (const float*)d_in[10];
    const float* W2   = (const float*)d_in[11];
    const float* b2   = (const float*)d_in[12];

    const int Btot = in_sizes[0] / TSTEPS;   // 131072

    lstm_fused<<<(Btot + BLK - 1) / BLK, BLK, 0, stream>>>(
        diag, Wih1, Whh1, bih1, bhh1,
        Wih2, Whh2, bih2, bhh2,
        W1, b1, W2, b2, (float*)d_out, Btot);
}

// Round 6
// 8792.687 us; speedup vs baseline: 3.6211x; 3.6211x over previous
//
#include <hip/hip_runtime.h>
#include <hip/hip_bf16.h>

#define HH 20
#define TSTEPS 256
#define FF 64
#define BLK 128

__device__ __forceinline__ float fast_sigm(float x) {
    float e = __expf(-x);                          // [0, inf)
    return __builtin_amdgcn_rcpf(1.0f + e);        // rcp(inf) = 0, safe
}
__device__ __forceinline__ float fast_tanh(float x) {
    // tanh(x) = 1 - 2/(1 + e^{2x}); e^{2x}->inf => 1, ->0 => -1. No overflow.
    float e = __expf(2.0f * x);
    return 1.0f - 2.0f * __builtin_amdgcn_rcpf(1.0f + e);
}

// One thread per batch element. Unit-rolled / k-unrolled structure:
//  - h state in VGPRs (no LDS read inside the FMA wall)
//  - weight rows contiguous -> wave-uniform s_load_dwordx8/x16 streams
//  - c + h staging in LDS [u][tid] (dynamic-u), ~6 ds ops per u-iter
__global__ __launch_bounds__(BLK) void lstm_fused(
    const float* __restrict__ diag,
    const float* __restrict__ Wih1,                 // [80] (in_dim = 1)
    const float* __restrict__ Whh1,                 // [80][20] row-major
    const float* __restrict__ bih1, const float* __restrict__ bhh1,
    const float* __restrict__ Wih2,                 // [80][20]
    const float* __restrict__ Whh2,                 // [80][20]
    const float* __restrict__ bih2, const float* __restrict__ bhh2,
    const float* __restrict__ W1,  const float* __restrict__ b1,   // [64][20], [64]
    const float* __restrict__ W2,  const float* __restrict__ b2,   // [64], [1]
    float* __restrict__ out, int Btot)
{
    __shared__ float s_c1[HH][BLK];   // cell state, layer 1
    __shared__ float s_c2[HH][BLK];   // cell state, layer 2
    __shared__ float s_h1[HH][BLK];   // h1' staging (dynamic-u write, static read)
    __shared__ float s_h2[HH][BLK];   // h2' staging
    const int tid = threadIdx.x;
    const int b = blockIdx.x * BLK + tid;
    if (b >= Btot) return;

    #pragma unroll
    for (int u = 0; u < HH; ++u) {
        s_c1[u][tid] = 0.0f; s_c2[u][tid] = 0.0f;
    }

    float h1[HH], h2[HH];
    #pragma unroll
    for (int k = 0; k < HH; ++k) { h1[k] = 0.0f; h2[k] = 0.0f; }

    const float* __restrict__ xr = diag + (long long)b * TSTEPS;
    float x = xr[0];

    #pragma unroll 1
    for (int t = 0; t < TSTEPS; ++t) {
        float xnext = xr[(t + 1) & (TSTEPS - 1)];   // prefetch (wraps; unused at end)

        // ================= layer 1 =================
        #pragma unroll 1
        for (int u = 0; u < HH; ++u) {
            const float* __restrict__ wi = Whh1 + (u         ) * HH;
            const float* __restrict__ wf = Whh1 + (u +     HH) * HH;
            const float* __restrict__ wg = Whh1 + (u + 2 * HH) * HH;
            const float* __restrict__ wo = Whh1 + (u + 3 * HH) * HH;
            float zi = fmaf(x, Wih1[u         ], bih1[u         ] + bhh1[u         ]);
            float zf = fmaf(x, Wih1[u +     HH], bih1[u +     HH] + bhh1[u +     HH]);
            float zg = fmaf(x, Wih1[u + 2 * HH], bih1[u + 2 * HH] + bhh1[u + 2 * HH]);
            float zo = fmaf(x, Wih1[u + 3 * HH], bih1[u + 3 * HH] + bhh1[u + 3 * HH]);
            #pragma unroll
            for (int k = 0; k < HH; ++k) {
                float hk = h1[k];
                zi = fmaf(hk, wi[k], zi);
                zf = fmaf(hk, wf[k], zf);
                zg = fmaf(hk, wg[k], zg);
                zo = fmaf(hk, wo[k], zo);
            }
            float c  = s_c1[u][tid];
            float cn = fast_sigm(zf) * c + fast_sigm(zi) * fast_tanh(zg);
            s_c1[u][tid] = cn;
            s_h1[u][tid] = fast_sigm(zo) * fast_tanh(cn);
        }
        // pull h1' into registers (static indices)
        float h1n[HH];
        #pragma unroll
        for (int k = 0; k < HH; ++k) h1n[k] = s_h1[k][tid];

        // ================= layer 2 =================
        #pragma unroll 1
        for (int u = 0; u < HH; ++u) {
            const float* __restrict__ vi = Wih2 + (u         ) * HH;
            const float* __restrict__ vf = Wih2 + (u +     HH) * HH;
            const float* __restrict__ vg = Wih2 + (u + 2 * HH) * HH;
            const float* __restrict__ vo = Wih2 + (u + 3 * HH) * HH;
            const float* __restrict__ wi = Whh2 + (u         ) * HH;
            const float* __restrict__ wf = Whh2 + (u +     HH) * HH;
            const float* __restrict__ wg = Whh2 + (u + 2 * HH) * HH;
            const float* __restrict__ wo = Whh2 + (u + 3 * HH) * HH;
            float zi = bih2[u         ] + bhh2[u         ];
            float zf = bih2[u +     HH] + bhh2[u +     HH];
            float zg = bih2[u + 2 * HH] + bhh2[u + 2 * HH];
            float zo = bih2[u + 3 * HH] + bhh2[u + 3 * HH];
            #pragma unroll
            for (int k = 0; k < HH; ++k) {
                float a  = h1n[k];
                float bb = h2[k];
                zi = fmaf(a, vi[k], zi); zi = fmaf(bb, wi[k], zi);
                zf = fmaf(a, vf[k], zf); zf = fmaf(bb, wf[k], zf);
                zg = fmaf(a, vg[k], zg); zg = fmaf(bb, wg[k], zg);
                zo = fmaf(a, vo[k], zo); zo = fmaf(bb, wo[k], zo);
            }
            float c  = s_c2[u][tid];
            float cn = fast_sigm(zf) * c + fast_sigm(zi) * fast_tanh(zg);
            s_c2[u][tid] = cn;
            s_h2[u][tid] = fast_sigm(zo) * fast_tanh(cn);
        }
        // pull h2' into registers; advance h1
        #pragma unroll
        for (int k = 0; k < HH; ++k) h2[k] = s_h2[k][tid];
        #pragma unroll
        for (int k = 0; k < HH; ++k) h1[k] = h1n[k];

        x = xnext;
    }

    // ---- head: relu(h2 @ W1^T + b1) -> relu(. @ W2^T + b2) ----
    float y2 = b2[0];
    #pragma unroll 1
    for (int j = 0; j < FF; ++j) {
        float a = b1[j];
        const float* __restrict__ wr = W1 + j * HH;
        #pragma unroll
        for (int k = 0; k < HH; ++k)
            a = fmaf(h2[k], wr[k], a);
        a = fmaxf(a, 0.0f);
        y2 = fmaf(a, W2[j], y2);
    }
    out[b] = fmaxf(y2, 0.0f);      // fp32 output, per reference dtype
}

extern "C" void kernel_launch(void* const* d_in, const int* in_sizes, int n_in,
                              void* d_out, int out_size, void* d_ws, size_t ws_size,
                              hipStream_t stream)
{
    (void)n_in; (void)ws_size; (void)out_size; (void)d_ws;
    const float* diag = (const float*)d_in[0];
    const float* Wih1 = (const float*)d_in[1];
    const float* Whh1 = (const float*)d_in[2];
    const float* bih1 = (const float*)d_in[3];
    const float* bhh1 = (const float*)d_in[4];
    const float* Wih2 = (const float*)d_in[5];
    const float* Whh2 = (const float*)d_in[6];
    const float* bih2 = (const float*)d_in[7];
    const float* bhh2 = (const float*)d_in[8];
    const float* W1   = (const float*)d_in[9];
    const float* b1   = (const float*)d_in[10];
    const float* W2   = (const float*)d_in[11];
    const float* b2   = (const float*)d_in[12];

    const int Btot = in_sizes[0] / TSTEPS;   // 131072

    lstm_fused<<<(Btot + BLK - 1) / BLK, BLK, 0, stream>>>(
        diag, Wih1, Whh1, bih1, bhh1,
        Wih2, Whh2, bih2, bhh2,
        W1, b1, W2, b2, (float*)d_out, Btot);
}